// Round 4
// baseline (512.427 us; speedup 1.0000x reference)
//
#include <hip/hip_runtime.h>
#include <hip/hip_bf16.h>

// GCN: 3x GCNConv (512->128->64->32) + global max pool + FC(32->10) + log_softmax
// N=100000 nodes, E=1600000 edges, 64 graphs.
//
// Round 10:
//  - Compact CSR instead of fixed [N][64] slab: per-node 4-int-aligned lists packed
//    into ~7.6MB 'edges' + one packed meta word per node ((start>>2)<<7 | deg).
//    Cuts per-gather adjacency traffic ~2-3x and lets the list cache across gathers.
//  - partition_edges EPB 6400 -> 3200 (500 blocks, 2/CU) for occupancy.
//  - Keeps round-9 fusions: gemm1 standalone; gather1+gemm2, gather2+gemm3,
//    gather3+pool fused; ACT/H3 never hit global.

typedef __attribute__((ext_vector_type(8))) short short8;
typedef __attribute__((ext_vector_type(8))) unsigned short ushort8v;
typedef __attribute__((ext_vector_type(4))) float f32x4;

constexpr int NB   = 1024;   // dst buckets (dst>>7)
constexpr int CAPB = 4096;   // edge capacity per bucket (mean 2046, sd ~45)
constexpr int EPB  = 3200;   // edges per partition block (500 blocks)

__device__ __forceinline__ unsigned short f2bf(float f) {
    __hip_bfloat16 h = __float2bfloat16(f);
    return *(unsigned short*)&h;
}
__device__ __forceinline__ float bfu2f(unsigned short u) {
    unsigned int v = ((unsigned int)u) << 16;
    return __uint_as_float(v);
}

// ---------------- setup: zero counters + pooled, transpose/convert weights ---------
__global__ void setup_kernel(const float* __restrict__ W1, const float* __restrict__ W2,
                             const float* __restrict__ W3,
                             unsigned short* __restrict__ Wt1, unsigned short* __restrict__ Wt2,
                             unsigned short* __restrict__ Wt3,
                             int* __restrict__ bcnt, int* __restrict__ gctr,
                             float* __restrict__ pooled) {
    int t = blockIdx.x * 256 + threadIdx.x;
    if (t == 0) gctr[0] = 0;
    if (t < NB * 16) bcnt[t] = 0;
    if (t < 64 * 32) pooled[t] = 0.0f;          // post-relu values >= 0
    if (t < 128 * 512) {                         // Wt1[n][k] = W1[k][n], 512x128
        int n = t >> 9, k = t & 511;
        Wt1[t] = f2bf(W1[(size_t)k * 128 + n]);
    } else if (t < 128 * 512 + 64 * 128) {       // Wt2, 128x64
        int u = t - 128 * 512;
        int n = u >> 7, k = u & 127;
        Wt2[u] = f2bf(W2[(size_t)k * 64 + n]);
    } else if (t < 128 * 512 + 64 * 128 + 32 * 64) {  // Wt3, 64x32
        int u = t - (128 * 512 + 64 * 128);
        int n = u >> 6, k = u & 63;
        Wt3[u] = f2bf(W3[(size_t)k * 32 + n]);
    }
}

// ---------------- P1: partition edges into dst-buckets (LDS-staged) ----------------
__global__ __launch_bounds__(256) void partition_edges(
        const int* __restrict__ src, const int* __restrict__ dst,
        int* __restrict__ bcnt, unsigned* __restrict__ bucketed, int E) {
    __shared__ unsigned h[NB], rs[NB], cur[NB], gs[NB];
    __shared__ unsigned wtot[4];
    __shared__ unsigned ebuf[EPB];
    __shared__ unsigned short ebkt[EPB];

    const int t = threadIdx.x;
    const int e0 = blockIdx.x * EPB;
    const int nloc = min(EPB, E - e0);

    for (int i = t; i < NB; i += 256) h[i] = 0;
    __syncthreads();

    for (int i = t; i < nloc; i += 256) {
        int d = dst[e0 + i];
        atomicAdd(&h[d >> 7], 1u);
    }
    __syncthreads();

    const unsigned b0 = 4u * t;
    unsigned s0 = h[b0], s1 = h[b0 + 1], s2 = h[b0 + 2], s3 = h[b0 + 3];
    unsigned tsum = s0 + s1 + s2 + s3;
    unsigned scan = tsum;
#pragma unroll
    for (int off = 1; off < 64; off <<= 1) {
        unsigned v = __shfl_up(scan, off, 64);
        if ((t & 63) >= off) scan += v;
    }
    if ((t & 63) == 63) wtot[t >> 6] = scan;
    __syncthreads();
    unsigned woff = 0;
    for (int w = 0; w < (t >> 6); ++w) woff += wtot[w];
    unsigned excl = woff + scan - tsum;
    rs[b0] = excl;                    cur[b0] = excl;
    rs[b0 + 1] = excl + s0;           cur[b0 + 1] = excl + s0;
    rs[b0 + 2] = excl + s0 + s1;      cur[b0 + 2] = excl + s0 + s1;
    rs[b0 + 3] = excl + s0 + s1 + s2; cur[b0 + 3] = excl + s0 + s1 + s2;
    if (s0) gs[b0]     = (unsigned)atomicAdd(&bcnt[(b0) * 16], (int)s0);
    if (s1) gs[b0 + 1] = (unsigned)atomicAdd(&bcnt[(b0 + 1) * 16], (int)s1);
    if (s2) gs[b0 + 2] = (unsigned)atomicAdd(&bcnt[(b0 + 2) * 16], (int)s2);
    if (s3) gs[b0 + 3] = (unsigned)atomicAdd(&bcnt[(b0 + 3) * 16], (int)s3);
    __syncthreads();

    for (int i = t; i < nloc; i += 256) {
        int d = dst[e0 + i];
        int s = src[e0 + i];
        int b = d >> 7;
        unsigned p = atomicAdd(&cur[b], 1u);
        ebuf[p] = ((unsigned)s << 7) | (unsigned)(d & 127);
        ebkt[p] = (unsigned short)b;
    }
    __syncthreads();

    for (int p = t; p < nloc; p += 256) {
        unsigned v = ebuf[p];
        int b = ebkt[p];
        unsigned g = gs[b] + ((unsigned)p - rs[b]);
        if (g < CAPB) bucketed[(size_t)b * CAPB + g] = v;
    }
}

// ---------------- P2: per-bucket compact CSR build in LDS ----------------
// meta[node] = (start4 << 7) | deg  (start4 = edge-list start in units of 4 ints)
__global__ __launch_bounds__(256) void bucket_csr(
        const unsigned* __restrict__ bucketed, const int* __restrict__ bcnt,
        unsigned* __restrict__ meta, int* __restrict__ edges,
        float* __restrict__ dinv, int* __restrict__ gctr, int N) {
    __shared__ int lcnt[128];
    __shared__ unsigned lslab[128 * 64];   // 32 KB
    __shared__ int loff[128];
    __shared__ int sbase;

    const int b = blockIdx.x;
    const int t = threadIdx.x;
    if (t < 128) lcnt[t] = 0;
    __syncthreads();

    int nE = bcnt[b * 16];
    if (nE > CAPB) nE = CAPB;
    const unsigned* bb = bucketed + (size_t)b * CAPB;
    for (int e = t; e < nE; e += 256) {
        unsigned v = bb[e];
        int ln = v & 127;
        int pos = atomicAdd(&lcnt[ln], 1);
        if (pos < 64) lslab[ln * 64 + pos] = v >> 7;
    }
    __syncthreads();

    // per-node capped deg, 4-int-aligned prefix within block
    int rawdeg = 0, deg = 0, pad = 0;
    if (t < 128) {
        rawdeg = lcnt[t];
        deg = min(rawdeg, 64);
        pad = (deg + 3) & ~3;
        loff[t] = pad;
    }
    __syncthreads();
#pragma unroll
    for (int off = 1; off < 128; off <<= 1) {
        int v = 0;
        if (t < 128 && t >= off) v = loff[t - off];
        __syncthreads();
        if (t < 128) loff[t] += v;
        __syncthreads();
    }
    if (t == 127) sbase = atomicAdd(gctr, loff[127]);
    __syncthreads();

    if (t < 128) {
        int node = b * 128 + t;
        if (node < N) {
            int start = sbase + loff[t] - pad;   // exclusive prefix, multiple of 4
            meta[node] = ((unsigned)(start >> 2) << 7) | (unsigned)deg;
            dinv[node] = rsqrtf(1.0f + (float)rawdeg);
            int4* dp = (int4*)&edges[start];
            const int4* sp = (const int4*)&lslab[t * 64];
            for (int i = 0; i < (deg + 3) / 4; ++i) dp[i] = sp[i];
        }
    }
}

// ---------------- MFMA GEMM: C_bf16[M x NOUT] = dinv .* (A[M x K] @ Wt^T) ----------
template <int NOUT, bool A_BF16>
__global__ __launch_bounds__(256) void mfma_gemm(
        const float* __restrict__ Af, const unsigned short* __restrict__ Ab,
        const unsigned short* __restrict__ Wt, const float* __restrict__ dinv,
        unsigned short* __restrict__ C, int M, int K) {
    constexpr int NT = NOUT / 16;
    constexpr int CH = 136;

    __shared__ short As[16 * CH];
    __shared__ short Bs[NT * 4 * CH];

    const int t = threadIdx.x;
    const int w = t >> 6;
    const int lane = t & 63;
    const int row0 = blockIdx.x * 64;

    f32x4 acc[NT];
#pragma unroll
    for (int c = 0; c < NT; ++c) acc[c] = (f32x4){0.f, 0.f, 0.f, 0.f};

    const int ar = t >> 2;
    const int aq = t & 3;
    const int arow = row0 + ar;
    const int a_lds = ((ar >> 4) * 4 + aq) * CH + (ar & 15) * 8;

    const int bn = t >> 1;
    const int bh = t & 1;
    const int b_lds0 = ((bn >> 4) * 4 + 2 * bh) * CH + (bn & 15) * 8;

    for (int k0 = 0; k0 < K; k0 += 32) {
        short8 apack;
        if (A_BF16) {
            if (arow < M) apack = *(const short8*)&Ab[(size_t)arow * K + k0 + aq * 8];
            else apack = (short8){0, 0, 0, 0, 0, 0, 0, 0};
        } else {
            float4 u0 = make_float4(0.f, 0.f, 0.f, 0.f), u1 = u0;
            if (arow < M) {
                const float* ap = Af + (size_t)arow * K + k0 + aq * 8;
                u0 = *(const float4*)ap;
                u1 = *(const float4*)(ap + 4);
            }
            apack[0] = (short)f2bf(u0.x); apack[1] = (short)f2bf(u0.y);
            apack[2] = (short)f2bf(u0.z); apack[3] = (short)f2bf(u0.w);
            apack[4] = (short)f2bf(u1.x); apack[5] = (short)f2bf(u1.y);
            apack[6] = (short)f2bf(u1.z); apack[7] = (short)f2bf(u1.w);
        }
        short8 w0, w1;
        if (t < 2 * NOUT) {
            const unsigned short* wp = Wt + (size_t)bn * K + k0 + 16 * bh;
            w0 = *(const short8*)wp;
            w1 = *(const short8*)(wp + 8);
        }
        __syncthreads();
        *(short8*)&As[a_lds] = apack;
        if (t < 2 * NOUT) {
            *(short8*)&Bs[b_lds0] = w0;
            *(short8*)&Bs[b_lds0 + CH] = w1;
        }
        __syncthreads();

        short8 a = *(short8*)&As[(w * 4 + (lane >> 4)) * CH + (lane & 15) * 8];
#pragma unroll
        for (int c = 0; c < NT; ++c) {
            short8 b = *(short8*)&Bs[(c * 4 + (lane >> 4)) * CH + (lane & 15) * 8];
            acc[c] = __builtin_amdgcn_mfma_f32_16x16x32_bf16(a, b, acc[c], 0, 0, 0);
        }
    }

    const int q = lane >> 4, i = lane & 15;
#pragma unroll
    for (int reg = 0; reg < 4; ++reg) {
        int row = row0 + w * 16 + q * 4 + reg;
        if (row < M) {
            float di = dinv[row];
#pragma unroll
            for (int c = 0; c < NT; ++c)
                C[(size_t)row * NOUT + c * 16 + i] = f2bf(di * acc[c][reg]);
        }
    }
}

// ---------------- shared gather inner loop (compact CSR, bf16 rows) ----------------
template <int F>
__device__ __forceinline__ void gather_acc(
        const unsigned* __restrict__ meta, const int* __restrict__ edges,
        const unsigned short* __restrict__ hs, int node, size_t fo, float acc[8]) {
    {
        ushort8v s = *(const ushort8v*)&hs[(size_t)node * F + fo];
#pragma unroll
        for (int i = 0; i < 8; ++i) acc[i] = bfu2f(s[i]);
    }
    const unsigned mv = meta[node];
    const int deg = (int)(mv & 127u);
    const int* sl = edges + ((size_t)(mv >> 7) << 2);

    int j = 0;
    for (; j + 8 <= deg; j += 8) {
        int4 a4 = *(const int4*)&sl[j];
        int4 b4 = *(const int4*)&sl[j + 4];
        ushort8v v0 = *(const ushort8v*)&hs[(size_t)a4.x * F + fo];
        ushort8v v1 = *(const ushort8v*)&hs[(size_t)a4.y * F + fo];
        ushort8v v2 = *(const ushort8v*)&hs[(size_t)a4.z * F + fo];
        ushort8v v3 = *(const ushort8v*)&hs[(size_t)a4.w * F + fo];
        ushort8v v4 = *(const ushort8v*)&hs[(size_t)b4.x * F + fo];
        ushort8v v5 = *(const ushort8v*)&hs[(size_t)b4.y * F + fo];
        ushort8v v6 = *(const ushort8v*)&hs[(size_t)b4.z * F + fo];
        ushort8v v7 = *(const ushort8v*)&hs[(size_t)b4.w * F + fo];
#pragma unroll
        for (int i = 0; i < 8; ++i)
            acc[i] += ((bfu2f(v0[i]) + bfu2f(v1[i])) + (bfu2f(v2[i]) + bfu2f(v3[i]))) +
                      ((bfu2f(v4[i]) + bfu2f(v5[i])) + (bfu2f(v6[i]) + bfu2f(v7[i])));
    }
    for (; j + 4 <= deg; j += 4) {
        int4 s4 = *(const int4*)&sl[j];
        ushort8v v0 = *(const ushort8v*)&hs[(size_t)s4.x * F + fo];
        ushort8v v1 = *(const ushort8v*)&hs[(size_t)s4.y * F + fo];
        ushort8v v2 = *(const ushort8v*)&hs[(size_t)s4.z * F + fo];
        ushort8v v3 = *(const ushort8v*)&hs[(size_t)s4.w * F + fo];
#pragma unroll
        for (int i = 0; i < 8; ++i)
            acc[i] += (bfu2f(v0[i]) + bfu2f(v1[i])) + (bfu2f(v2[i]) + bfu2f(v3[i]));
    }
    for (; j < deg; ++j) {
        int s = sl[j];
        ushort8v v = *(const ushort8v*)&hs[(size_t)s * F + fo];
#pragma unroll
        for (int i = 0; i < 8; ++i) acc[i] += bfu2f(v[i]);
    }
}

// ---------------- fused gather+relu (layer l) + linear (layer l+1) ------------------
template <int F, int NOUT>
__global__ __launch_bounds__(256) void gather_gemm(
        const unsigned* __restrict__ meta, const int* __restrict__ edges,
        const float* __restrict__ dinv, const unsigned short* __restrict__ hs,
        const float* __restrict__ bias, const unsigned short* __restrict__ Wt,
        unsigned short* __restrict__ Cout, int N) {
    constexpr int F8 = F / 8;
    constexpr int NPB = 256 / F8;        // 16 (F=128) or 32 (F=64)
    constexpr int LDA = F + 8;
    constexpr int MT = NPB / 16;
    constexpr int KS = F / 32;

    __shared__ short At[NPB * LDA];
    __shared__ short Bs[NOUT * LDA];

    const int t = threadIdx.x;
    const int node0 = blockIdx.x * NPB;
    const int nl = t / F8;
    const int lf = t % F8;
    const int node = node0 + nl;
    const size_t fo = (size_t)lf * 8;

#pragma unroll
    for (int idx = t * 8; idx < NOUT * F; idx += 256 * 8) {
        int r = idx / F, k = idx % F;
        *(short8*)&Bs[r * LDA + k] = *(const short8*)&Wt[idx];
    }

    short8 arow = (short8){0, 0, 0, 0, 0, 0, 0, 0};
    if (node < N) {
        float acc[8];
        gather_acc<F>(meta, edges, hs, node, fo, acc);
        const float di = dinv[node];
#pragma unroll
        for (int i = 0; i < 8; ++i)
            arow[i] = (short)f2bf(fmaxf(di * acc[i] + bias[fo + i], 0.f));
    }
    *(short8*)&At[nl * LDA + lf * 8] = arow;
    __syncthreads();

    const int w = t >> 6, l = t & 63;
    const int m = (MT == 1) ? 0 : (w >> 1);
    const int c = (MT == 1) ? w : (w & 1);
    f32x4 acc4 = (f32x4){0.f, 0.f, 0.f, 0.f};
#pragma unroll
    for (int ks = 0; ks < KS; ++ks) {
        short8 a = *(short8*)&At[(m * 16 + (l & 15)) * LDA + ks * 32 + (l >> 4) * 8];
        short8 b = *(short8*)&Bs[(c * 16 + (l & 15)) * LDA + ks * 32 + (l >> 4) * 8];
        acc4 = __builtin_amdgcn_mfma_f32_16x16x32_bf16(a, b, acc4, 0, 0, 0);
    }
    const int q = l >> 4, i = l & 15;
#pragma unroll
    for (int reg = 0; reg < 4; ++reg) {
        int grow = node0 + m * 16 + q * 4 + reg;
        if (grow < N)
            Cout[(size_t)grow * NOUT + c * 16 + i] = f2bf(dinv[grow] * acc4[reg]);
    }
}

// ---------------- fused gather3 + relu + segment-max pool ----------------
__global__ __launch_bounds__(256) void gather_pool(
        const unsigned* __restrict__ meta, const int* __restrict__ edges,
        const float* __restrict__ dinv, const unsigned short* __restrict__ hs,
        const float* __restrict__ bias, const int* __restrict__ batch,
        float* __restrict__ pooled, int N) {
    constexpr int F = 32, F8 = 4, NPB = 64;
    __shared__ float P[NPB * 32];
    __shared__ int gbuf[NPB];

    const int t = threadIdx.x;
    const int node0 = blockIdx.x * NPB;
    const int nl = t >> 2, lf = t & 3;
    const int node = node0 + nl;
    const size_t fo = (size_t)lf * 8;

    float ov[8] = {0.f, 0.f, 0.f, 0.f, 0.f, 0.f, 0.f, 0.f};
    if (node < N) {
        float acc[8];
        gather_acc<F>(meta, edges, hs, node, fo, acc);
        const float di = dinv[node];
#pragma unroll
        for (int i = 0; i < 8; ++i) ov[i] = fmaxf(di * acc[i] + bias[fo + i], 0.f);
    }
#pragma unroll
    for (int i = 0; i < 8; ++i) P[nl * 32 + lf * 8 + i] = ov[i];
    if (t < NPB) gbuf[t] = (node0 + t < N) ? batch[node0 + t] : -1;
    __syncthreads();

    if (t < 32) {
        int gcur = -1;
        float vmax = 0.f;
        for (int j = 0; j < NPB; ++j) {
            int g = gbuf[j];
            if (g < 0) break;
            if (g != gcur) {
                if (gcur >= 0) atomicMax((int*)&pooled[gcur * 32 + t], __float_as_int(vmax));
                gcur = g;
                vmax = 0.f;
            }
            vmax = fmaxf(vmax, P[j * 32 + t]);
        }
        if (gcur >= 0) atomicMax((int*)&pooled[gcur * 32 + t], __float_as_int(vmax));
    }
}

// ---------------- head ----------------
__global__ void head_kernel(const float* __restrict__ pooled, const float* __restrict__ Wfc,
                            const float* __restrict__ bfc, float* __restrict__ out) {
    int g = threadIdx.x;  // 64 graphs
    float p[32];
#pragma unroll
    for (int f = 0; f < 32; ++f) p[f] = pooled[g * 32 + f];
    float logits[10];
#pragma unroll
    for (int c = 0; c < 10; ++c) {
        float acc = bfc[c];
#pragma unroll
        for (int f = 0; f < 32; ++f) acc += p[f] * Wfc[f * 10 + c];
        logits[c] = acc;
    }
    float m = logits[0];
#pragma unroll
    for (int c = 1; c < 10; ++c) m = fmaxf(m, logits[c]);
    float s = 0.f;
#pragma unroll
    for (int c = 0; c < 10; ++c) s += expf(logits[c] - m);
    float lse = m + logf(s);
#pragma unroll
    for (int c = 0; c < 10; ++c) out[g * 10 + c] = logits[c] - lse;
}

extern "C" void kernel_launch(void* const* d_in, const int* in_sizes, int n_in,
                              void* d_out, int out_size, void* d_ws, size_t ws_size,
                              hipStream_t stream) {
    const float* x   = (const float*)d_in[0];
    const int*   ei  = (const int*)d_in[1];
    const int*   bat = (const int*)d_in[2];
    const float* W1  = (const float*)d_in[3];
    const float* b1  = (const float*)d_in[4];
    const float* W2  = (const float*)d_in[5];
    const float* b2  = (const float*)d_in[6];
    const float* W3  = (const float*)d_in[7];
    const float* b3  = (const float*)d_in[8];
    const float* Wfc = (const float*)d_in[9];
    const float* bfc = (const float*)d_in[10];
    float* out = (float*)d_out;

    const int N = in_sizes[2];        // 100000
    const int E = in_sizes[1] / 2;    // 1600000
    const int K0 = in_sizes[0] / N;   // 512

    const int* src = ei;
    const int* dst = ei + E;

    float* ws = (float*)d_ws;
    float* dinv = ws;                                        // N f32
    unsigned short* HS  = (unsigned short*)(ws + N);         // N*128 bf16 (gemm1 out)
    unsigned short* HS2 = HS + (size_t)N * 128;              // N*64 bf16
    unsigned short* HS3 = HS2 + (size_t)N * 64;              // N*32 bf16
    float* pooled = (float*)(HS3 + (size_t)N * 32);          // 2048 f32
    unsigned short* Wt1 = (unsigned short*)(pooled + 2048);  // 128*512 bf16
    unsigned short* Wt2 = Wt1 + 128 * 512;                   // 64*128
    unsigned short* Wt3 = Wt2 + 64 * 128;                    // 32*64
    unsigned* meta = (unsigned*)(Wt3 + 32 * 64);             // N u32 (start4<<7 | deg)
    int* edges = (int*)(meta + N);                           // <= E + 3N ints (compact CSR)
    int* gctr = edges + (E + 3 * N + 64);                    // 1 int
    int* bcnt = gctr + 16;                                   // NB*16 (64B-padded counters)
    unsigned* bucketed = (unsigned*)(bcnt + NB * 16);        // NB*CAPB packed (src<<7|ln)

    const int gb = (N + 63) / 64;
    const int NBUCK = (N + 127) >> 7;

    // ---- setup (zero counters/pooled, convert weights) ----
    setup_kernel<<<(128 * 512 + 64 * 128 + 32 * 64 + 255) / 256, 256, 0, stream>>>(
        W1, W2, W3, Wt1, Wt2, Wt3, bcnt, gctr, pooled);

    // ---- CSR build: partition by dst-bucket, then per-bucket compact CSR ----
    partition_edges<<<(E + EPB - 1) / EPB, 256, 0, stream>>>(src, dst, bcnt, bucketed, E);
    bucket_csr<<<NBUCK, 256, 0, stream>>>(bucketed, bcnt, meta, edges, dinv, gctr, N);

    // ---- layer 1 GEMM: 512 -> 128 (A = x f32) ----
    mfma_gemm<128, false><<<gb, 256, 0, stream>>>(x, nullptr, Wt1, dinv, HS, N, K0);

    // ---- gather1 + gemm2 fused: HS -> HS2 ----
    gather_gemm<128, 64><<<(N + 15) / 16, 256, 0, stream>>>(
        meta, edges, dinv, HS, b1, Wt2, HS2, N);

    // ---- gather2 + gemm3 fused: HS2 -> HS3 ----
    gather_gemm<64, 32><<<(N + 31) / 32, 256, 0, stream>>>(
        meta, edges, dinv, HS2, b2, Wt3, HS3, N);

    // ---- gather3 + relu + pool fused ----
    gather_pool<<<(N + 63) / 64, 256, 0, stream>>>(meta, edges, dinv, HS3, b3, bat, pooled, N);

    // ---- head ----
    head_kernel<<<1, 64, 0, stream>>>(pooled, Wfc, bfc, out);
}

// Round 5
// 507.068 us; speedup vs baseline: 1.0106x; 1.0106x over previous
//
#include <hip/hip_runtime.h>
#include <hip/hip_bf16.h>

// GCN: 3x GCNConv (512->128->64->32) + global max pool + FC(32->10) + log_softmax
// N=100000 nodes, E=1600000 edges, 64 graphs.
//
// Round 11:
//  - Round-10 post-mortem: compact CSR regressed (503->512): meta->edges dependent
//    chain on the gather critical path + serial scan/copy in bucket_csr. REVERTED
//    to round-9 slab CSR (fixed [N][64] slab, cnt, EPB=6400).
//  - Gathers are latency-bound (~2.3 TB/s effective, well under HBM/L2 ceilings):
//    software-pipelined gather_acc -- prefetch next batch's slab int4 pair before
//    accumulating current batch, hiding neighbor-list latency under row loads.

typedef __attribute__((ext_vector_type(8))) short short8;
typedef __attribute__((ext_vector_type(8))) unsigned short ushort8v;
typedef __attribute__((ext_vector_type(4))) float f32x4;

constexpr int NB   = 1024;   // dst buckets (dst>>7)
constexpr int CAPB = 4096;   // edge capacity per bucket (mean 2046, sd ~45)
constexpr int EPB  = 6400;   // edges per partition block (250 blocks)

__device__ __forceinline__ unsigned short f2bf(float f) {
    __hip_bfloat16 h = __float2bfloat16(f);
    return *(unsigned short*)&h;
}
__device__ __forceinline__ float bfu2f(unsigned short u) {
    unsigned int v = ((unsigned int)u) << 16;
    return __uint_as_float(v);
}

// ---------------- setup: zero bucket counters + pooled, transpose/convert weights ---
__global__ void setup_kernel(const float* __restrict__ W1, const float* __restrict__ W2,
                             const float* __restrict__ W3,
                             unsigned short* __restrict__ Wt1, unsigned short* __restrict__ Wt2,
                             unsigned short* __restrict__ Wt3,
                             int* __restrict__ bcnt, float* __restrict__ pooled) {
    int t = blockIdx.x * 256 + threadIdx.x;
    if (t < NB * 16) bcnt[t] = 0;
    if (t < 64 * 32) pooled[t] = 0.0f;          // post-relu values >= 0
    if (t < 128 * 512) {                         // Wt1[n][k] = W1[k][n], 512x128
        int n = t >> 9, k = t & 511;
        Wt1[t] = f2bf(W1[(size_t)k * 128 + n]);
    } else if (t < 128 * 512 + 64 * 128) {       // Wt2, 128x64
        int u = t - 128 * 512;
        int n = u >> 7, k = u & 127;
        Wt2[u] = f2bf(W2[(size_t)k * 64 + n]);
    } else if (t < 128 * 512 + 64 * 128 + 32 * 64) {  // Wt3, 64x32
        int u = t - (128 * 512 + 64 * 128);
        int n = u >> 6, k = u & 63;
        Wt3[u] = f2bf(W3[(size_t)k * 32 + n]);
    }
}

// ---------------- P1: partition edges into dst-buckets (LDS-staged) ----------------
__global__ __launch_bounds__(256) void partition_edges(
        const int* __restrict__ src, const int* __restrict__ dst,
        int* __restrict__ bcnt, unsigned* __restrict__ bucketed, int E) {
    __shared__ unsigned h[NB], rs[NB], cur[NB], gs[NB];
    __shared__ unsigned wtot[4];
    __shared__ unsigned ebuf[EPB];
    __shared__ unsigned short ebkt[EPB];

    const int t = threadIdx.x;
    const int e0 = blockIdx.x * EPB;
    const int nloc = min(EPB, E - e0);

    for (int i = t; i < NB; i += 256) h[i] = 0;
    __syncthreads();

    for (int i = t; i < nloc; i += 256) {
        int d = dst[e0 + i];
        atomicAdd(&h[d >> 7], 1u);
    }
    __syncthreads();

    const unsigned b0 = 4u * t;
    unsigned s0 = h[b0], s1 = h[b0 + 1], s2 = h[b0 + 2], s3 = h[b0 + 3];
    unsigned tsum = s0 + s1 + s2 + s3;
    unsigned scan = tsum;
#pragma unroll
    for (int off = 1; off < 64; off <<= 1) {
        unsigned v = __shfl_up(scan, off, 64);
        if ((t & 63) >= off) scan += v;
    }
    if ((t & 63) == 63) wtot[t >> 6] = scan;
    __syncthreads();
    unsigned woff = 0;
    for (int w = 0; w < (t >> 6); ++w) woff += wtot[w];
    unsigned excl = woff + scan - tsum;
    rs[b0] = excl;                    cur[b0] = excl;
    rs[b0 + 1] = excl + s0;           cur[b0 + 1] = excl + s0;
    rs[b0 + 2] = excl + s0 + s1;      cur[b0 + 2] = excl + s0 + s1;
    rs[b0 + 3] = excl + s0 + s1 + s2; cur[b0 + 3] = excl + s0 + s1 + s2;
    if (s0) gs[b0]     = (unsigned)atomicAdd(&bcnt[(b0) * 16], (int)s0);
    if (s1) gs[b0 + 1] = (unsigned)atomicAdd(&bcnt[(b0 + 1) * 16], (int)s1);
    if (s2) gs[b0 + 2] = (unsigned)atomicAdd(&bcnt[(b0 + 2) * 16], (int)s2);
    if (s3) gs[b0 + 3] = (unsigned)atomicAdd(&bcnt[(b0 + 3) * 16], (int)s3);
    __syncthreads();

    for (int i = t; i < nloc; i += 256) {
        int d = dst[e0 + i];
        int s = src[e0 + i];
        int b = d >> 7;
        unsigned p = atomicAdd(&cur[b], 1u);
        ebuf[p] = ((unsigned)s << 7) | (unsigned)(d & 127);
        ebkt[p] = (unsigned short)b;
    }
    __syncthreads();

    for (int p = t; p < nloc; p += 256) {
        unsigned v = ebuf[p];
        int b = ebkt[p];
        unsigned g = gs[b] + ((unsigned)p - rs[b]);
        if (g < CAPB) bucketed[(size_t)b * CAPB + g] = v;
    }
}

// ---------------- P2: per-bucket CSR (slab) build in LDS ----------------
__global__ __launch_bounds__(256) void bucket_csr(
        const unsigned* __restrict__ bucketed, const int* __restrict__ bcnt,
        int* __restrict__ cnt, int* __restrict__ slab, float* __restrict__ dinv, int N) {
    __shared__ int lcnt[128];
    __shared__ unsigned lslab[128 * 64];   // 32 KB

    const int b = blockIdx.x;
    const int t = threadIdx.x;
    if (t < 128) lcnt[t] = 0;
    __syncthreads();

    int nE = bcnt[b * 16];
    if (nE > CAPB) nE = CAPB;
    const unsigned* bb = bucketed + (size_t)b * CAPB;
    for (int e = t; e < nE; e += 256) {
        unsigned v = bb[e];
        int ln = v & 127;
        int pos = atomicAdd(&lcnt[ln], 1);
        if (pos < 64) lslab[ln * 64 + pos] = v >> 7;
    }
    __syncthreads();

    const int node0 = b * 128;
    const int nnodes = min(128, N - node0);
    if (nnodes <= 0) return;
    const int tot4 = (nnodes * 64) / 4;
    int4* gout = (int4*)&slab[(size_t)node0 * 64];
    const int4* lin = (const int4*)lslab;
    for (int i = t; i < tot4; i += 256) gout[i] = lin[i];
    if (t < nnodes) {
        int deg = lcnt[t];
        cnt[node0 + t] = deg;
        dinv[node0 + t] = rsqrtf(1.0f + (float)deg);
    }
}

// ---------------- MFMA GEMM: C_bf16[M x NOUT] = dinv .* (A[M x K] @ Wt^T) ----------
template <int NOUT, bool A_BF16>
__global__ __launch_bounds__(256) void mfma_gemm(
        const float* __restrict__ Af, const unsigned short* __restrict__ Ab,
        const unsigned short* __restrict__ Wt, const float* __restrict__ dinv,
        unsigned short* __restrict__ C, int M, int K) {
    constexpr int NT = NOUT / 16;
    constexpr int CH = 136;

    __shared__ short As[16 * CH];
    __shared__ short Bs[NT * 4 * CH];

    const int t = threadIdx.x;
    const int w = t >> 6;
    const int lane = t & 63;
    const int row0 = blockIdx.x * 64;

    f32x4 acc[NT];
#pragma unroll
    for (int c = 0; c < NT; ++c) acc[c] = (f32x4){0.f, 0.f, 0.f, 0.f};

    const int ar = t >> 2;
    const int aq = t & 3;
    const int arow = row0 + ar;
    const int a_lds = ((ar >> 4) * 4 + aq) * CH + (ar & 15) * 8;

    const int bn = t >> 1;
    const int bh = t & 1;
    const int b_lds0 = ((bn >> 4) * 4 + 2 * bh) * CH + (bn & 15) * 8;

    for (int k0 = 0; k0 < K; k0 += 32) {
        short8 apack;
        if (A_BF16) {
            if (arow < M) apack = *(const short8*)&Ab[(size_t)arow * K + k0 + aq * 8];
            else apack = (short8){0, 0, 0, 0, 0, 0, 0, 0};
        } else {
            float4 u0 = make_float4(0.f, 0.f, 0.f, 0.f), u1 = u0;
            if (arow < M) {
                const float* ap = Af + (size_t)arow * K + k0 + aq * 8;
                u0 = *(const float4*)ap;
                u1 = *(const float4*)(ap + 4);
            }
            apack[0] = (short)f2bf(u0.x); apack[1] = (short)f2bf(u0.y);
            apack[2] = (short)f2bf(u0.z); apack[3] = (short)f2bf(u0.w);
            apack[4] = (short)f2bf(u1.x); apack[5] = (short)f2bf(u1.y);
            apack[6] = (short)f2bf(u1.z); apack[7] = (short)f2bf(u1.w);
        }
        short8 w0, w1;
        if (t < 2 * NOUT) {
            const unsigned short* wp = Wt + (size_t)bn * K + k0 + 16 * bh;
            w0 = *(const short8*)wp;
            w1 = *(const short8*)(wp + 8);
        }
        __syncthreads();
        *(short8*)&As[a_lds] = apack;
        if (t < 2 * NOUT) {
            *(short8*)&Bs[b_lds0] = w0;
            *(short8*)&Bs[b_lds0 + CH] = w1;
        }
        __syncthreads();

        short8 a = *(short8*)&As[(w * 4 + (lane >> 4)) * CH + (lane & 15) * 8];
#pragma unroll
        for (int c = 0; c < NT; ++c) {
            short8 b = *(short8*)&Bs[(c * 4 + (lane >> 4)) * CH + (lane & 15) * 8];
            acc[c] = __builtin_amdgcn_mfma_f32_16x16x32_bf16(a, b, acc[c], 0, 0, 0);
        }
    }

    const int q = lane >> 4, i = lane & 15;
#pragma unroll
    for (int reg = 0; reg < 4; ++reg) {
        int row = row0 + w * 16 + q * 4 + reg;
        if (row < M) {
            float di = dinv[row];
#pragma unroll
            for (int c = 0; c < NT; ++c)
                C[(size_t)row * NOUT + c * 16 + i] = f2bf(di * acc[c][reg]);
        }
    }
}

// ---------------- shared gather inner loop (slab adjacency, pipelined) -------------
template <int F>
__device__ __forceinline__ void gather_acc(
        const int* __restrict__ cnt, const int* __restrict__ slab,
        const unsigned short* __restrict__ hs, int node, size_t fo, float acc[8]) {
    {
        ushort8v s = *(const ushort8v*)&hs[(size_t)node * F + fo];
#pragma unroll
        for (int i = 0; i < 8; ++i) acc[i] = bfu2f(s[i]);
    }
    int deg = cnt[node];
    if (deg > 64) deg = 64;
    const int* sl = slab + (size_t)node * 64;

    int j = 0;
    if (deg >= 8) {
        // software pipeline: slab int4s for batch j prefetched at batch j-8
        int4 a4 = *(const int4*)&sl[0];
        int4 b4 = *(const int4*)&sl[4];
        for (; j + 16 <= deg; j += 8) {
            int4 na = *(const int4*)&sl[j + 8];
            int4 nb = *(const int4*)&sl[j + 12];
            ushort8v v0 = *(const ushort8v*)&hs[(size_t)a4.x * F + fo];
            ushort8v v1 = *(const ushort8v*)&hs[(size_t)a4.y * F + fo];
            ushort8v v2 = *(const ushort8v*)&hs[(size_t)a4.z * F + fo];
            ushort8v v3 = *(const ushort8v*)&hs[(size_t)a4.w * F + fo];
            ushort8v v4 = *(const ushort8v*)&hs[(size_t)b4.x * F + fo];
            ushort8v v5 = *(const ushort8v*)&hs[(size_t)b4.y * F + fo];
            ushort8v v6 = *(const ushort8v*)&hs[(size_t)b4.z * F + fo];
            ushort8v v7 = *(const ushort8v*)&hs[(size_t)b4.w * F + fo];
#pragma unroll
            for (int i = 0; i < 8; ++i)
                acc[i] += ((bfu2f(v0[i]) + bfu2f(v1[i])) + (bfu2f(v2[i]) + bfu2f(v3[i]))) +
                          ((bfu2f(v4[i]) + bfu2f(v5[i])) + (bfu2f(v6[i]) + bfu2f(v7[i])));
            a4 = na; b4 = nb;
        }
        // last full 8-batch (registers already loaded)
        {
            ushort8v v0 = *(const ushort8v*)&hs[(size_t)a4.x * F + fo];
            ushort8v v1 = *(const ushort8v*)&hs[(size_t)a4.y * F + fo];
            ushort8v v2 = *(const ushort8v*)&hs[(size_t)a4.z * F + fo];
            ushort8v v3 = *(const ushort8v*)&hs[(size_t)a4.w * F + fo];
            ushort8v v4 = *(const ushort8v*)&hs[(size_t)b4.x * F + fo];
            ushort8v v5 = *(const ushort8v*)&hs[(size_t)b4.y * F + fo];
            ushort8v v6 = *(const ushort8v*)&hs[(size_t)b4.z * F + fo];
            ushort8v v7 = *(const ushort8v*)&hs[(size_t)b4.w * F + fo];
#pragma unroll
            for (int i = 0; i < 8; ++i)
                acc[i] += ((bfu2f(v0[i]) + bfu2f(v1[i])) + (bfu2f(v2[i]) + bfu2f(v3[i]))) +
                          ((bfu2f(v4[i]) + bfu2f(v5[i])) + (bfu2f(v6[i]) + bfu2f(v7[i])));
            j += 8;
        }
    }
    for (; j + 4 <= deg; j += 4) {
        int4 s4 = *(const int4*)&sl[j];
        ushort8v v0 = *(const ushort8v*)&hs[(size_t)s4.x * F + fo];
        ushort8v v1 = *(const ushort8v*)&hs[(size_t)s4.y * F + fo];
        ushort8v v2 = *(const ushort8v*)&hs[(size_t)s4.z * F + fo];
        ushort8v v3 = *(const ushort8v*)&hs[(size_t)s4.w * F + fo];
#pragma unroll
        for (int i = 0; i < 8; ++i)
            acc[i] += (bfu2f(v0[i]) + bfu2f(v1[i])) + (bfu2f(v2[i]) + bfu2f(v3[i]));
    }
    for (; j < deg; ++j) {
        int s = sl[j];
        ushort8v v = *(const ushort8v*)&hs[(size_t)s * F + fo];
#pragma unroll
        for (int i = 0; i < 8; ++i) acc[i] += bfu2f(v[i]);
    }
}

// ---------------- fused gather+relu (layer l) + linear (layer l+1) ------------------
template <int F, int NOUT>
__global__ __launch_bounds__(256) void gather_gemm(
        const int* __restrict__ cnt, const int* __restrict__ slab,
        const float* __restrict__ dinv, const unsigned short* __restrict__ hs,
        const float* __restrict__ bias, const unsigned short* __restrict__ Wt,
        unsigned short* __restrict__ Cout, int N) {
    constexpr int F8 = F / 8;
    constexpr int NPB = 256 / F8;        // 16 (F=128) or 32 (F=64)
    constexpr int LDA = F + 8;
    constexpr int MT = NPB / 16;
    constexpr int KS = F / 32;

    __shared__ short At[NPB * LDA];
    __shared__ short Bs[NOUT * LDA];

    const int t = threadIdx.x;
    const int node0 = blockIdx.x * NPB;
    const int nl = t / F8;
    const int lf = t % F8;
    const int node = node0 + nl;
    const size_t fo = (size_t)lf * 8;

#pragma unroll
    for (int idx = t * 8; idx < NOUT * F; idx += 256 * 8) {
        int r = idx / F, k = idx % F;
        *(short8*)&Bs[r * LDA + k] = *(const short8*)&Wt[idx];
    }

    short8 arow = (short8){0, 0, 0, 0, 0, 0, 0, 0};
    if (node < N) {
        float acc[8];
        gather_acc<F>(cnt, slab, hs, node, fo, acc);
        const float di = dinv[node];
#pragma unroll
        for (int i = 0; i < 8; ++i)
            arow[i] = (short)f2bf(fmaxf(di * acc[i] + bias[fo + i], 0.f));
    }
    *(short8*)&At[nl * LDA + lf * 8] = arow;
    __syncthreads();

    const int w = t >> 6, l = t & 63;
    const int m = (MT == 1) ? 0 : (w >> 1);
    const int c = (MT == 1) ? w : (w & 1);
    f32x4 acc4 = (f32x4){0.f, 0.f, 0.f, 0.f};
#pragma unroll
    for (int ks = 0; ks < KS; ++ks) {
        short8 a = *(short8*)&At[(m * 16 + (l & 15)) * LDA + ks * 32 + (l >> 4) * 8];
        short8 b = *(short8*)&Bs[(c * 16 + (l & 15)) * LDA + ks * 32 + (l >> 4) * 8];
        acc4 = __builtin_amdgcn_mfma_f32_16x16x32_bf16(a, b, acc4, 0, 0, 0);
    }
    const int q = l >> 4, i = l & 15;
#pragma unroll
    for (int reg = 0; reg < 4; ++reg) {
        int grow = node0 + m * 16 + q * 4 + reg;
        if (grow < N)
            Cout[(size_t)grow * NOUT + c * 16 + i] = f2bf(dinv[grow] * acc4[reg]);
    }
}

// ---------------- fused gather3 + relu + segment-max pool ----------------
__global__ __launch_bounds__(256) void gather_pool(
        const int* __restrict__ cnt, const int* __restrict__ slab,
        const float* __restrict__ dinv, const unsigned short* __restrict__ hs,
        const float* __restrict__ bias, const int* __restrict__ batch,
        float* __restrict__ pooled, int N) {
    constexpr int F = 32, F8 = 4, NPB = 64;
    __shared__ float P[NPB * 32];
    __shared__ int gbuf[NPB];

    const int t = threadIdx.x;
    const int node0 = blockIdx.x * NPB;
    const int nl = t >> 2, lf = t & 3;
    const int node = node0 + nl;
    const size_t fo = (size_t)lf * 8;

    float ov[8] = {0.f, 0.f, 0.f, 0.f, 0.f, 0.f, 0.f, 0.f};
    if (node < N) {
        float acc[8];
        gather_acc<F>(cnt, slab, hs, node, fo, acc);
        const float di = dinv[node];
#pragma unroll
        for (int i = 0; i < 8; ++i) ov[i] = fmaxf(di * acc[i] + bias[fo + i], 0.f);
    }
#pragma unroll
    for (int i = 0; i < 8; ++i) P[nl * 32 + lf * 8 + i] = ov[i];
    if (t < NPB) gbuf[t] = (node0 + t < N) ? batch[node0 + t] : -1;
    __syncthreads();

    if (t < 32) {
        int gcur = -1;
        float vmax = 0.f;
        for (int j = 0; j < NPB; ++j) {
            int g = gbuf[j];
            if (g < 0) break;
            if (g != gcur) {
                if (gcur >= 0) atomicMax((int*)&pooled[gcur * 32 + t], __float_as_int(vmax));
                gcur = g;
                vmax = 0.f;
            }
            vmax = fmaxf(vmax, P[j * 32 + t]);
        }
        if (gcur >= 0) atomicMax((int*)&pooled[gcur * 32 + t], __float_as_int(vmax));
    }
}

// ---------------- head ----------------
__global__ void head_kernel(const float* __restrict__ pooled, const float* __restrict__ Wfc,
                            const float* __restrict__ bfc, float* __restrict__ out) {
    int g = threadIdx.x;  // 64 graphs
    float p[32];
#pragma unroll
    for (int f = 0; f < 32; ++f) p[f] = pooled[g * 32 + f];
    float logits[10];
#pragma unroll
    for (int c = 0; c < 10; ++c) {
        float acc = bfc[c];
#pragma unroll
        for (int f = 0; f < 32; ++f) acc += p[f] * Wfc[f * 10 + c];
        logits[c] = acc;
    }
    float m = logits[0];
#pragma unroll
    for (int c = 1; c < 10; ++c) m = fmaxf(m, logits[c]);
    float s = 0.f;
#pragma unroll
    for (int c = 0; c < 10; ++c) s += expf(logits[c] - m);
    float lse = m + logf(s);
#pragma unroll
    for (int c = 0; c < 10; ++c) out[g * 10 + c] = logits[c] - lse;
}

extern "C" void kernel_launch(void* const* d_in, const int* in_sizes, int n_in,
                              void* d_out, int out_size, void* d_ws, size_t ws_size,
                              hipStream_t stream) {
    const float* x   = (const float*)d_in[0];
    const int*   ei  = (const int*)d_in[1];
    const int*   bat = (const int*)d_in[2];
    const float* W1  = (const float*)d_in[3];
    const float* b1  = (const float*)d_in[4];
    const float* W2  = (const float*)d_in[5];
    const float* b2  = (const float*)d_in[6];
    const float* W3  = (const float*)d_in[7];
    const float* b3  = (const float*)d_in[8];
    const float* Wfc = (const float*)d_in[9];
    const float* bfc = (const float*)d_in[10];
    float* out = (float*)d_out;

    const int N = in_sizes[2];        // 100000
    const int E = in_sizes[1] / 2;    // 1600000
    const int K0 = in_sizes[0] / N;   // 512

    const int* src = ei;
    const int* dst = ei + E;

    float* ws = (float*)d_ws;
    float* dinv = ws;                                        // N f32
    unsigned short* HS  = (unsigned short*)(ws + N);         // N*128 bf16 (gemm1 out)
    unsigned short* HS2 = HS + (size_t)N * 128;              // N*64 bf16
    unsigned short* HS3 = HS2 + (size_t)N * 64;              // N*32 bf16
    float* pooled = (float*)(HS3 + (size_t)N * 32);          // 2048 f32
    unsigned short* Wt1 = (unsigned short*)(pooled + 2048);  // 128*512 bf16
    unsigned short* Wt2 = Wt1 + 128 * 512;                   // 64*128
    unsigned short* Wt3 = Wt2 + 64 * 128;                    // 32*64
    int* cnt = (int*)(Wt3 + 32 * 64);                        // N
    int* slab = cnt + N;                                     // N*64
    int* bcnt = slab + (size_t)N * 64;                       // NB*16 (64B-padded counters)
    unsigned* bucketed = (unsigned*)(bcnt + NB * 16);        // NB*CAPB packed (src<<7|ln)

    const int gb = (N + 63) / 64;
    const int NBUCK = (N + 127) >> 7;

    // ---- setup (zero counters/pooled, convert weights) ----
    setup_kernel<<<(128 * 512 + 64 * 128 + 32 * 64 + 255) / 256, 256, 0, stream>>>(
        W1, W2, W3, Wt1, Wt2, Wt3, bcnt, pooled);

    // ---- CSR build: partition by dst-bucket, then per-bucket LDS slab ----
    partition_edges<<<(E + EPB - 1) / EPB, 256, 0, stream>>>(src, dst, bcnt, bucketed, E);
    bucket_csr<<<NBUCK, 256, 0, stream>>>(bucketed, bcnt, cnt, slab, dinv, N);

    // ---- layer 1 GEMM: 512 -> 128 (A = x f32) ----
    mfma_gemm<128, false><<<gb, 256, 0, stream>>>(x, nullptr, Wt1, dinv, HS, N, K0);

    // ---- gather1 + gemm2 fused: HS -> HS2 ----
    gather_gemm<128, 64><<<(N + 15) / 16, 256, 0, stream>>>(
        cnt, slab, dinv, HS, b1, Wt2, HS2, N);

    // ---- gather2 + gemm3 fused: HS2 -> HS3 ----
    gather_gemm<64, 32><<<(N + 31) / 32, 256, 0, stream>>>(
        cnt, slab, dinv, HS2, b2, Wt3, HS3, N);

    // ---- gather3 + relu + pool fused ----
    gather_pool<<<(N + 63) / 64, 256, 0, stream>>>(cnt, slab, dinv, HS3, b3, bat, pooled, N);

    // ---- head ----
    head_kernel<<<1, 64, 0, stream>>>(pooled, Wfc, bfc, out);
}